// Round 20
// baseline (432.564 us; speedup 1.0000x reference)
//
#include <hip/hip_runtime.h>

#define N_NODES 50000
#define N_EDGES 1600000
#define F_IN 1433
#define HID 128
#define NCLS 7
#define KSTEPS 45
#define SLABS 12   // ceil(45/4) K-slabs of 4 steps (BK=128)

// ---- workspace layout (bytes), all 256-aligned ----
#define O_DEG_SRC 0u          // N ints   (200000)
#define O_DEG_DST 200704u     // N ints
#define O_CURSOR  401408u     // N ints
#define O_ROWPTR  602112u     // N+1 ints
#define O_NSRC    802816u     // N floats
#define O_NDST    1003520u    // N floats
#define O_BSUM    1204224u    // 256 ints
#define O_BOFF    1205248u    // 256 ints
#define O_CSR     1206272u    // E ints (6400000)
#define O_H       7606272u    // N*128 _Float16 (12800000), 16B aligned
#define O_H2      33206272u   // N*8 floats padded (1600000)
#define O_W1S     34806272u   // 45*4096 _Float16 = 368640 B (fp16, staged granule order)

#define GEMM_BLOCKS 782   // even indices 0..1562 -> gemm (i>>1)
#define MEGA_BLOCKS 1564  // odd indices -> fill (782 fill blocks)

typedef __attribute__((ext_vector_type(4))) float f4v;       // 4 f32
typedef __attribute__((ext_vector_type(8))) _Float16 h8v;    // 8 fp16 (16B, 4 VGPRs)

// ---- prep: zero counters (blocks 0..146) + W1 fp16 granule repack (147..236) ----
__global__ void prep_kernel(int4* __restrict__ zp, const float* __restrict__ W1,
                            _Float16* __restrict__ W1S) {
    if (blockIdx.x < 147) {
        int i = blockIdx.x * 256 + threadIdx.x;
        if (i < 37632) zp[i] = make_int4(0, 0, 0, 0);  // deg_src/deg_dst/cursor
        return;
    }
    int t = (blockIdx.x - 147) * 256 + threadIdx.x;  // (s*4 + k4)*128 + n, total 23040
    if (t >= KSTEPS * 4 * 128) return;
    int n = t & 127;
    int k4 = (t >> 7) & 3;
    int s = t >> 9;
    long base = (long)s * 4096 + (k4 * 128 + n) * 8;
#pragma unroll
    for (int j = 0; j < 8; j++) {
        int k = s * 32 + k4 * 8 + j;
        W1S[base + j] = (_Float16)((k < F_IN) ? W1[(long)k * HID + n] : 0.f);
    }
}

// both degrees, int4-vectorized (4 edges/thread)
__global__ void deg_kernel(const int4* __restrict__ src4, const int4* __restrict__ dst4,
                           int* __restrict__ deg_src, int* __restrict__ deg_dst) {
    int i = blockIdx.x * blockDim.x + threadIdx.x;
    if (i < N_EDGES / 4) {
        int4 s = src4[i], d = dst4[i];
        atomicAdd(&deg_src[s.x], 1); atomicAdd(&deg_src[s.y], 1);
        atomicAdd(&deg_src[s.z], 1); atomicAdd(&deg_src[s.w], 1);
        atomicAdd(&deg_dst[d.x], 1); atomicAdd(&deg_dst[d.y], 1);
        atomicAdd(&deg_dst[d.z], 1); atomicAdd(&deg_dst[d.w], 1);
    }
}

__global__ void scan1_kernel(const int* __restrict__ deg, int* __restrict__ incl,
                             int* __restrict__ bsum) {
    __shared__ int s[256];
    int t = threadIdx.x;
    int i = blockIdx.x * 256 + t;
    int v = (i < N_NODES) ? deg[i] : 0;
    s[t] = v;
    __syncthreads();
    for (int off = 1; off < 256; off <<= 1) {
        int a = (t >= off) ? s[t - off] : 0;
        __syncthreads();
        s[t] += a;
        __syncthreads();
    }
    if (i < N_NODES) incl[i] = s[t];
    if (t == 255) bsum[blockIdx.x] = s[255];
}

__global__ void scan2_kernel(const int* __restrict__ bsum, int* __restrict__ boff, int nb) {
    __shared__ int s[256];
    int t = threadIdx.x;
    int v = (t < nb) ? bsum[t] : 0;
    s[t] = v;
    __syncthreads();
    for (int off = 1; off < 256; off <<= 1) {
        int a = (t >= off) ? s[t - off] : 0;
        __syncthreads();
        s[t] += a;
        __syncthreads();
    }
    if (t < nb) boff[t] = s[t] - v;  // exclusive
}

// rowptr finalize + BOTH norms
__global__ void scan3_kernel(int* __restrict__ rowptr, const int* __restrict__ deg_dst,
                             const int* __restrict__ deg_src, const int* __restrict__ boff,
                             float* __restrict__ nsrc, float* __restrict__ ndst) {
    int i = blockIdx.x * 256 + threadIdx.x;
    if (i < N_NODES) {
        int dd = deg_dst[i];
        rowptr[i] = rowptr[i] - dd + boff[blockIdx.x];
        ndst[i] = rsqrtf(fmaxf((float)dd, 1.0f));
        nsrc[i] = rsqrtf(fmaxf((float)deg_src[i], 1.0f));
    }
}

// ---- MEGA kernel: INTERLEAVED roles — even blocks gemm, odd blocks fill ----
// so the resident set on every CU mixes gemm (latency-stalled) and fill
// (atomic/scatter) waves from t=0; fill rides in gemm's issue shadows.
#define GBM 64
__global__ __launch_bounds__(256, 3) void mega_kernel(const float* __restrict__ X,
                                                      const _Float16* __restrict__ W1S,
                                                      const float* __restrict__ nsrc,
                                                      _Float16* __restrict__ h,
                                                      const int4* __restrict__ src4,
                                                      const int4* __restrict__ dst4,
                                                      const int* __restrict__ rowptr,
                                                      int* __restrict__ cursor,
                                                      int* __restrict__ csr) {
    __shared__ __align__(16) _Float16 xs[8192];    // 16 KB
    __shared__ __align__(16) _Float16 bs[16384];   // 32 KB

    const int half = blockIdx.x >> 1;
    if (blockIdx.x & 1) {
        // ---------------- fill branch (782 blocks, grid-stride) ----------------
        int gtid = half * 256 + threadIdx.x;
        for (int i = gtid; i < N_EDGES / 4; i += GEMM_BLOCKS * 256) {
            int4 s = src4[i], d = dst4[i];
            int p0 = rowptr[d.x] + atomicAdd(&cursor[d.x], 1);
            csr[p0] = s.x;
            int p1 = rowptr[d.y] + atomicAdd(&cursor[d.y], 1);
            csr[p1] = s.y;
            int p2 = rowptr[d.z] + atomicAdd(&cursor[d.z], 1);
            csr[p2] = s.z;
            int p3 = rowptr[d.w] + atomicAdd(&cursor[d.w], 1);
            csr[p3] = s.w;
        }
        return;
    }

    // ---------------- gemm branch (r18 slab-phased) ----------------
    const int tid = threadIdx.x;
    const int l = tid & 63, w = tid >> 6;
    const int wm = w >> 1, wn = w & 1;
    const int k4r = l >> 4, l15 = l & 15;
    const int bm = half * GBM;

    const int sr = tid >> 2, sq = tid & 3;
    const int srow = bm + sr;
    const bool sok = srow < N_NODES;
    const float* Xrow = X + (long)(sok ? srow : 0) * F_IN;

    float4 xreg[8];
    h8v breg[8];

#define LOAD_SLAB(SL)                                                              \
    do {                                                                           \
        int _cb = (SL) * 128 + sq * 32;                                            \
        if (sok && _cb + 32 <= F_IN) {                                             \
            _Pragma("unroll") for (int _i = 0; _i < 8; _i++)                       \
                xreg[_i] = *(const float4*)(Xrow + _cb + 4 * _i);                  \
        } else {                                                                   \
            _Pragma("unroll") for (int _i = 0; _i < 8; _i++) {                     \
                float4 _v = make_float4(0.f, 0.f, 0.f, 0.f);                       \
                int _c = _cb + 4 * _i;                                             \
                if (sok && _c < F_IN) {                                            \
                    if (_c + 4 <= F_IN) _v = *(const float4*)(Xrow + _c);          \
                    else {                                                         \
                        _v.x = Xrow[_c];                                           \
                        if (_c + 1 < F_IN) _v.y = Xrow[_c + 1];                    \
                        if (_c + 2 < F_IN) _v.z = Xrow[_c + 2];                    \
                    }                                                              \
                }                                                                  \
                xreg[_i] = _v;                                                     \
            }                                                                      \
        }                                                                          \
        _Pragma("unroll") for (int _i = 0; _i < 8; _i++) {                         \
            long _g = (long)(SL) * 2048 + _i * 256 + tid;                          \
            h8v _bv = {};                                                          \
            if (_g < (long)KSTEPS * 512) _bv = *(const h8v*)(W1S + _g * 8);        \
            breg[_i] = _bv;                                                        \
        }                                                                          \
    } while (0)

#define STORE_SLAB()                                                               \
    do {                                                                           \
        _Pragma("unroll") for (int _k4 = 0; _k4 < 4; _k4++) {                      \
            float4 _a = xreg[2 * _k4], _b = xreg[2 * _k4 + 1];                     \
            h8v _v = {(_Float16)_a.x, (_Float16)_a.y, (_Float16)_a.z,              \
                      (_Float16)_a.w, (_Float16)_b.x, (_Float16)_b.y,              \
                      (_Float16)_b.z, (_Float16)_b.w};                             \
            *(h8v*)&xs[((sq * 4 + _k4) * 64 + sr) * 8] = _v;                       \
        }                                                                          \
        _Pragma("unroll") for (int _i = 0; _i < 8; _i++)                           \
            *(h8v*)&bs[(_i * 256 + tid) * 8] = breg[_i];                           \
    } while (0)

    f4v acc[2][4];
#pragma unroll
    for (int i = 0; i < 2; i++)
#pragma unroll
        for (int j = 0; j < 4; j++) acc[i][j] = (f4v){0.f, 0.f, 0.f, 0.f};

    LOAD_SLAB(0);
    for (int sl = 0; sl < SLABS; ++sl) {
        STORE_SLAB();
        __syncthreads();
        if (sl + 1 < SLABS) LOAD_SLAB(sl + 1);
#pragma unroll
        for (int j = 0; j < 4; j++) {
            if (sl * 4 + j < KSTEPS) {
                h8v afr[2];
#pragma unroll
                for (int mf = 0; mf < 2; mf++)
                    afr[mf] = *(const h8v*)&xs[((j * 4 + k4r) * 64 + wm * 32 + mf * 16 + l15) * 8];
                h8v bfr[4];
#pragma unroll
                for (int nf = 0; nf < 4; nf++)
                    bfr[nf] = *(const h8v*)&bs[(j * 512 + k4r * 128 + wn * 64 + nf * 16 + l15) * 8];
#pragma unroll
                for (int mf = 0; mf < 2; mf++)
#pragma unroll
                    for (int nf = 0; nf < 4; nf++)
                        acc[mf][nf] = __builtin_amdgcn_mfma_f32_16x16x32_f16(
                            afr[mf], bfr[nf], acc[mf][nf], 0, 0, 0);
            }
        }
        __syncthreads();
    }

#pragma unroll
    for (int mf = 0; mf < 2; mf++) {
        int row0 = bm + wm * 32 + mf * 16 + (l >> 4) * 4;
#pragma unroll
        for (int nf = 0; nf < 4; nf++) {
            int col = wn * 64 + nf * 16 + l15;
#pragma unroll
            for (int r = 0; r < 4; r++) {
                int row = row0 + r;
                if (row < N_NODES) h[(long)row * HID + col] = (_Float16)(nsrc[row] * acc[mf][nf][r]);
            }
        }
    }
#undef LOAD_SLAB
#undef STORE_SLAB
}

// ---- agg1: 16-lane group per node, 4 rows per wave-load, unroll 8 ----
__global__ __launch_bounds__(256) void agg1_kernel(const _Float16* __restrict__ h,
                                                   const int* __restrict__ csr,
                                                   const int* __restrict__ rowptr,
                                                   const int* __restrict__ deg,
                                                   const float* __restrict__ ndst,
                                                   const float* __restrict__ nsrc,
                                                   const float* __restrict__ b1,
                                                   const float* __restrict__ W2,
                                                   float* __restrict__ h2p) {
    const int lane = threadIdx.x & 63;
    const int wave = threadIdx.x >> 6;
    const int fl = lane & 15;
    const int node = blockIdx.x * 16 + wave * 4 + (lane >> 4);
    const bool active = node < N_NODES;
    int p = active ? rowptr[node] : 0;
    int end = active ? p + deg[node] : 0;

    float acc[8];
#pragma unroll
    for (int j = 0; j < 8; j++) acc[j] = 0.f;
    const _Float16* hb = h + fl * 8;

    for (; p + 8 <= end; p += 8) {
        int i0 = csr[p], i1 = csr[p + 1], i2 = csr[p + 2], i3 = csr[p + 3];
        int i4 = csr[p + 4], i5 = csr[p + 5], i6 = csr[p + 6], i7 = csr[p + 7];
        h8v a0 = *(const h8v*)(hb + (long)i0 * HID);
        h8v a1 = *(const h8v*)(hb + (long)i1 * HID);
        h8v a2 = *(const h8v*)(hb + (long)i2 * HID);
        h8v a3 = *(const h8v*)(hb + (long)i3 * HID);
        h8v a4 = *(const h8v*)(hb + (long)i4 * HID);
        h8v a5 = *(const h8v*)(hb + (long)i5 * HID);
        h8v a6 = *(const h8v*)(hb + (long)i6 * HID);
        h8v a7 = *(const h8v*)(hb + (long)i7 * HID);
#pragma unroll
        for (int j = 0; j < 8; j++)
            acc[j] += (((float)a0[j] + (float)a1[j]) + ((float)a2[j] + (float)a3[j])) +
                      (((float)a4[j] + (float)a5[j]) + ((float)a6[j] + (float)a7[j]));
    }
    for (; p < end; ++p) {
        int i0 = csr[p];
        h8v a0 = *(const h8v*)(hb + (long)i0 * HID);
#pragma unroll
        for (int j = 0; j < 8; j++) acc[j] += (float)a0[j];
    }

    float nd = active ? ndst[node] : 0.f;
    float ns = active ? nsrc[node] : 0.f;
    float x[8];
#pragma unroll
    for (int j = 0; j < 8; j++)
        x[j] = fmaxf(acc[j] * nd + b1[fl * 8 + j], 0.f) * ns;

    float q[NCLS];
#pragma unroll
    for (int c = 0; c < NCLS; c++) {
        float s = 0.f;
#pragma unroll
        for (int j = 0; j < 8; j++) s += x[j] * W2[(fl * 8 + j) * NCLS + c];
        q[c] = s;
    }
#pragma unroll
    for (int c = 0; c < NCLS; c++) {
#pragma unroll
        for (int off = 1; off < 16; off <<= 1) q[c] += __shfl_xor(q[c], off);
    }
    if (active) {
        if (fl < NCLS) h2p[(long)node * 8 + fl] = q[fl];
        if (fl == 7) h2p[(long)node * 8 + 7] = 0.f;
    }
}

// per dst node: out = (sum h2[src]) * nd + b2  (h2 stride-8, 2x float4 per edge)
__global__ __launch_bounds__(256) void agg2_kernel(const float* __restrict__ h2p,
                                                   const int* __restrict__ csr,
                                                   const int* __restrict__ rowptr,
                                                   const int* __restrict__ deg,
                                                   const float* __restrict__ ndst,
                                                   const float* __restrict__ b2,
                                                   float* __restrict__ out) {
    int wid = threadIdx.x >> 6, lane = threadIdx.x & 63;
    int node = blockIdx.x * 4 + wid;
    if (node >= N_NODES) return;
    int rp = rowptr[node], end = rp + deg[node];
    float a0 = 0.f, a1 = 0.f, a2 = 0.f, a3 = 0.f, a4 = 0.f, a5 = 0.f, a6 = 0.f;
    for (int p = rp + lane; p < end; p += 64) {
        int s = csr[p];
        const float4* r = (const float4*)(h2p + (long)s * 8);
        float4 lo = r[0], hi = r[1];
        a0 += lo.x; a1 += lo.y; a2 += lo.z; a3 += lo.w;
        a4 += hi.x; a5 += hi.y; a6 += hi.z;
    }
    float nd = ndst[node];
    float acc[NCLS] = {a0, a1, a2, a3, a4, a5, a6};
#pragma unroll
    for (int c = 0; c < NCLS; c++) {
        float v = acc[c];
#pragma unroll
        for (int off = 1; off < 64; off <<= 1) v += __shfl_xor(v, off);
        if (lane == c) out[(long)node * NCLS + c] = v * nd + b2[c];
    }
}

extern "C" void kernel_launch(void* const* d_in, const int* in_sizes, int n_in,
                              void* d_out, int out_size, void* d_ws, size_t ws_size,
                              hipStream_t stream) {
    const float* X  = (const float*)d_in[0];
    const int* src  = (const int*)d_in[1];
    const int* dst  = (const int*)d_in[2];
    const float* W1 = (const float*)d_in[3];
    const float* b1 = (const float*)d_in[4];
    const float* W2 = (const float*)d_in[5];
    const float* b2 = (const float*)d_in[6];
    float* out = (float*)d_out;

    char* ws = (char*)d_ws;
    int* deg_src = (int*)(ws + O_DEG_SRC);
    int* deg_dst = (int*)(ws + O_DEG_DST);
    int* cursor  = (int*)(ws + O_CURSOR);
    int* rowptr  = (int*)(ws + O_ROWPTR);
    float* nsrc  = (float*)(ws + O_NSRC);
    float* ndst  = (float*)(ws + O_NDST);
    int* bsum    = (int*)(ws + O_BSUM);
    int* boff    = (int*)(ws + O_BOFF);
    int* csr     = (int*)(ws + O_CSR);
    _Float16* h  = (_Float16*)(ws + O_H);
    float* h2p   = (float*)(ws + O_H2);
    _Float16* W1S = (_Float16*)(ws + O_W1S);

    const int nb = (N_NODES + 255) / 256;  // 196
    prep_kernel<<<237, 256, 0, stream>>>((int4*)ws, W1, W1S);
    deg_kernel<<<(N_EDGES / 4 + 255) / 256, 256, 0, stream>>>((const int4*)src, (const int4*)dst,
                                                              deg_src, deg_dst);
    scan1_kernel<<<nb, 256, 0, stream>>>(deg_dst, rowptr, bsum);
    scan2_kernel<<<1, 256, 0, stream>>>(bsum, boff, nb);
    scan3_kernel<<<nb, 256, 0, stream>>>(rowptr, deg_dst, deg_src, boff, nsrc, ndst);

    mega_kernel<<<MEGA_BLOCKS, 256, 0, stream>>>(
        X, W1S, nsrc, h, (const int4*)src, (const int4*)dst, rowptr, cursor, csr);

    agg1_kernel<<<(N_NODES + 15) / 16, 256, 0, stream>>>(h, csr, rowptr, deg_dst, ndst, nsrc,
                                                         b1, W2, h2p);
    agg2_kernel<<<(N_NODES + 3) / 4, 256, 0, stream>>>(h2p, csr, rowptr, deg_dst, ndst, b2, out);
}

// Round 21
// 389.672 us; speedup vs baseline: 1.1101x; 1.1101x over previous
//
#include <hip/hip_runtime.h>

#define N_NODES 50000
#define N_EDGES 1600000
#define F_IN 1433
#define HID 128
#define NCLS 7
#define KSTEPS 45
#define SLABS 12   // ceil(45/4) K-slabs of 4 steps (BK=128)

// ---- workspace layout (bytes), all 256-aligned ----
#define O_DEG_SRC 0u          // N ints   (200000)
#define O_DEG_DST 200704u     // N ints
#define O_CURSOR  401408u     // N ints
#define O_ROWPTR  602112u     // N+1 ints
#define O_NSRC    802816u     // N floats
#define O_NDST    1003520u    // N floats
#define O_BSUM    1204224u    // 256 ints
#define O_BOFF    1205248u    // 256 ints
#define O_CSR     1206272u    // E ints (6400000)
#define O_H       7606272u    // N*128 _Float16 (12800000), 16B aligned
#define O_H2      33206272u   // N*8 floats padded (1600000)
#define O_W1S     34806272u   // 45*4096 _Float16 = 368640 B (fp16, staged granule order)

#define GEMM_BLOCKS 782
#define FILL_BLOCKS 1024

typedef __attribute__((ext_vector_type(4))) float f4v;       // 4 f32
typedef __attribute__((ext_vector_type(8))) _Float16 h8v;    // 8 fp16 (16B, 4 VGPRs)

// ---- prep: zero counters (blocks 0..146) + W1 fp16 granule repack (147..236) ----
__global__ void prep_kernel(int4* __restrict__ zp, const float* __restrict__ W1,
                            _Float16* __restrict__ W1S) {
    if (blockIdx.x < 147) {
        int i = blockIdx.x * 256 + threadIdx.x;
        if (i < 37632) zp[i] = make_int4(0, 0, 0, 0);  // deg_src/deg_dst/cursor
        return;
    }
    int t = (blockIdx.x - 147) * 256 + threadIdx.x;  // (s*4 + k4)*128 + n, total 23040
    if (t >= KSTEPS * 4 * 128) return;
    int n = t & 127;
    int k4 = (t >> 7) & 3;
    int s = t >> 9;
    long base = (long)s * 4096 + (k4 * 128 + n) * 8;
#pragma unroll
    for (int j = 0; j < 8; j++) {
        int k = s * 32 + k4 * 8 + j;
        W1S[base + j] = (_Float16)((k < F_IN) ? W1[(long)k * HID + n] : 0.f);
    }
}

// both degrees, int4-vectorized (4 edges/thread)
__global__ void deg_kernel(const int4* __restrict__ src4, const int4* __restrict__ dst4,
                           int* __restrict__ deg_src, int* __restrict__ deg_dst) {
    int i = blockIdx.x * blockDim.x + threadIdx.x;
    if (i < N_EDGES / 4) {
        int4 s = src4[i], d = dst4[i];
        atomicAdd(&deg_src[s.x], 1); atomicAdd(&deg_src[s.y], 1);
        atomicAdd(&deg_src[s.z], 1); atomicAdd(&deg_src[s.w], 1);
        atomicAdd(&deg_dst[d.x], 1); atomicAdd(&deg_dst[d.y], 1);
        atomicAdd(&deg_dst[d.z], 1); atomicAdd(&deg_dst[d.w], 1);
    }
}

__global__ void scan1_kernel(const int* __restrict__ deg, int* __restrict__ incl,
                             int* __restrict__ bsum) {
    __shared__ int s[256];
    int t = threadIdx.x;
    int i = blockIdx.x * 256 + t;
    int v = (i < N_NODES) ? deg[i] : 0;
    s[t] = v;
    __syncthreads();
    for (int off = 1; off < 256; off <<= 1) {
        int a = (t >= off) ? s[t - off] : 0;
        __syncthreads();
        s[t] += a;
        __syncthreads();
    }
    if (i < N_NODES) incl[i] = s[t];
    if (t == 255) bsum[blockIdx.x] = s[255];
}

__global__ void scan2_kernel(const int* __restrict__ bsum, int* __restrict__ boff, int nb) {
    __shared__ int s[256];
    int t = threadIdx.x;
    int v = (t < nb) ? bsum[t] : 0;
    s[t] = v;
    __syncthreads();
    for (int off = 1; off < 256; off <<= 1) {
        int a = (t >= off) ? s[t - off] : 0;
        __syncthreads();
        s[t] += a;
        __syncthreads();
    }
    if (t < nb) boff[t] = s[t] - v;  // exclusive
}

// rowptr finalize + BOTH norms
__global__ void scan3_kernel(int* __restrict__ rowptr, const int* __restrict__ deg_dst,
                             const int* __restrict__ deg_src, const int* __restrict__ boff,
                             float* __restrict__ nsrc, float* __restrict__ ndst) {
    int i = blockIdx.x * 256 + threadIdx.x;
    if (i < N_NODES) {
        int dd = deg_dst[i];
        rowptr[i] = rowptr[i] - dd + boff[blockIdx.x];
        ndst[i] = rsqrtf(fmaxf((float)dd, 1.0f));
        nsrc[i] = rsqrtf(fmaxf((float)deg_src[i], 1.0f));
    }
}

// ---- MEGA kernel: blocks 0..781 = slab-phased GEMM1; blocks 782+ = CSR fill ----
#define GBM 64
__global__ __launch_bounds__(256, 3) void mega_kernel(const float* __restrict__ X,
                                                      const _Float16* __restrict__ W1S,
                                                      const float* __restrict__ nsrc,
                                                      _Float16* __restrict__ h,
                                                      const int4* __restrict__ src4,
                                                      const int4* __restrict__ dst4,
                                                      const int* __restrict__ rowptr,
                                                      int* __restrict__ cursor,
                                                      int* __restrict__ csr) {
    __shared__ __align__(16) _Float16 xs[8192];    // 16 KB
    __shared__ __align__(16) _Float16 bs[16384];   // 32 KB

    if (blockIdx.x >= GEMM_BLOCKS) {
        // ---------------- fill branch ----------------
        int gtid = (blockIdx.x - GEMM_BLOCKS) * 256 + threadIdx.x;
        for (int i = gtid; i < N_EDGES / 4; i += FILL_BLOCKS * 256) {
            int4 s = src4[i], d = dst4[i];
            int p0 = rowptr[d.x] + atomicAdd(&cursor[d.x], 1);
            csr[p0] = s.x;
            int p1 = rowptr[d.y] + atomicAdd(&cursor[d.y], 1);
            csr[p1] = s.y;
            int p2 = rowptr[d.z] + atomicAdd(&cursor[d.z], 1);
            csr[p2] = s.z;
            int p3 = rowptr[d.w] + atomicAdd(&cursor[d.w], 1);
            csr[p3] = s.w;
        }
        return;
    }

    // ---------------- gemm branch (r18 slab-phased) ----------------
    const int tid = threadIdx.x;
    const int l = tid & 63, w = tid >> 6;
    const int wm = w >> 1, wn = w & 1;
    const int k4r = l >> 4, l15 = l & 15;
    const int bm = blockIdx.x * GBM;

    const int sr = tid >> 2, sq = tid & 3;
    const int srow = bm + sr;
    const bool sok = srow < N_NODES;
    const float* Xrow = X + (long)(sok ? srow : 0) * F_IN;

    float4 xreg[8];
    h8v breg[8];

#define LOAD_SLAB(SL)                                                              \
    do {                                                                           \
        int _cb = (SL) * 128 + sq * 32;                                            \
        if (sok && _cb + 32 <= F_IN) {                                             \
            _Pragma("unroll") for (int _i = 0; _i < 8; _i++)                       \
                xreg[_i] = *(const float4*)(Xrow + _cb + 4 * _i);                  \
        } else {                                                                   \
            _Pragma("unroll") for (int _i = 0; _i < 8; _i++) {                     \
                float4 _v = make_float4(0.f, 0.f, 0.f, 0.f);                       \
                int _c = _cb + 4 * _i;                                             \
                if (sok && _c < F_IN) {                                            \
                    if (_c + 4 <= F_IN) _v = *(const float4*)(Xrow + _c);          \
                    else {                                                         \
                        _v.x = Xrow[_c];                                           \
                        if (_c + 1 < F_IN) _v.y = Xrow[_c + 1];                    \
                        if (_c + 2 < F_IN) _v.z = Xrow[_c + 2];                    \
                    }                                                              \
                }                                                                  \
                xreg[_i] = _v;                                                     \
            }                                                                      \
        }                                                                          \
        _Pragma("unroll") for (int _i = 0; _i < 8; _i++) {                         \
            long _g = (long)(SL) * 2048 + _i * 256 + tid;                          \
            h8v _bv = {};                                                          \
            if (_g < (long)KSTEPS * 512) _bv = *(const h8v*)(W1S + _g * 8);        \
            breg[_i] = _bv;                                                        \
        }                                                                          \
    } while (0)

#define STORE_SLAB()                                                               \
    do {                                                                           \
        _Pragma("unroll") for (int _k4 = 0; _k4 < 4; _k4++) {                      \
            float4 _a = xreg[2 * _k4], _b = xreg[2 * _k4 + 1];                     \
            h8v _v = {(_Float16)_a.x, (_Float16)_a.y, (_Float16)_a.z,              \
                      (_Float16)_a.w, (_Float16)_b.x, (_Float16)_b.y,              \
                      (_Float16)_b.z, (_Float16)_b.w};                             \
            *(h8v*)&xs[((sq * 4 + _k4) * 64 + sr) * 8] = _v;                       \
        }                                                                          \
        _Pragma("unroll") for (int _i = 0; _i < 8; _i++)                           \
            *(h8v*)&bs[(_i * 256 + tid) * 8] = breg[_i];                           \
    } while (0)

    f4v acc[2][4];
#pragma unroll
    for (int i = 0; i < 2; i++)
#pragma unroll
        for (int j = 0; j < 4; j++) acc[i][j] = (f4v){0.f, 0.f, 0.f, 0.f};

    LOAD_SLAB(0);
    for (int sl = 0; sl < SLABS; ++sl) {
        STORE_SLAB();
        __syncthreads();
        if (sl + 1 < SLABS) LOAD_SLAB(sl + 1);
#pragma unroll
        for (int j = 0; j < 4; j++) {
            if (sl * 4 + j < KSTEPS) {
                h8v afr[2];
#pragma unroll
                for (int mf = 0; mf < 2; mf++)
                    afr[mf] = *(const h8v*)&xs[((j * 4 + k4r) * 64 + wm * 32 + mf * 16 + l15) * 8];
                h8v bfr[4];
#pragma unroll
                for (int nf = 0; nf < 4; nf++)
                    bfr[nf] = *(const h8v*)&bs[(j * 512 + k4r * 128 + wn * 64 + nf * 16 + l15) * 8];
#pragma unroll
                for (int mf = 0; mf < 2; mf++)
#pragma unroll
                    for (int nf = 0; nf < 4; nf++)
                        acc[mf][nf] = __builtin_amdgcn_mfma_f32_16x16x32_f16(
                            afr[mf], bfr[nf], acc[mf][nf], 0, 0, 0);
            }
        }
        __syncthreads();
    }

#pragma unroll
    for (int mf = 0; mf < 2; mf++) {
        int row0 = bm + wm * 32 + mf * 16 + (l >> 4) * 4;
#pragma unroll
        for (int nf = 0; nf < 4; nf++) {
            int col = wn * 64 + nf * 16 + l15;
#pragma unroll
            for (int r = 0; r < 4; r++) {
                int row = row0 + r;
                if (row < N_NODES) h[(long)row * HID + col] = (_Float16)(nsrc[row] * acc[mf][nf][r]);
            }
        }
    }
#undef LOAD_SLAB
#undef STORE_SLAB
}

// ---- agg1: 16-lane group per node, 4 rows per wave-load, unroll 8 ----
__global__ __launch_bounds__(256) void agg1_kernel(const _Float16* __restrict__ h,
                                                   const int* __restrict__ csr,
                                                   const int* __restrict__ rowptr,
                                                   const int* __restrict__ deg,
                                                   const float* __restrict__ ndst,
                                                   const float* __restrict__ nsrc,
                                                   const float* __restrict__ b1,
                                                   const float* __restrict__ W2,
                                                   float* __restrict__ h2p) {
    const int lane = threadIdx.x & 63;
    const int wave = threadIdx.x >> 6;
    const int fl = lane & 15;
    const int node = blockIdx.x * 16 + wave * 4 + (lane >> 4);
    const bool active = node < N_NODES;
    int p = active ? rowptr[node] : 0;
    int end = active ? p + deg[node] : 0;

    float acc[8];
#pragma unroll
    for (int j = 0; j < 8; j++) acc[j] = 0.f;
    const _Float16* hb = h + fl * 8;

    for (; p + 8 <= end; p += 8) {
        int i0 = csr[p], i1 = csr[p + 1], i2 = csr[p + 2], i3 = csr[p + 3];
        int i4 = csr[p + 4], i5 = csr[p + 5], i6 = csr[p + 6], i7 = csr[p + 7];
        h8v a0 = *(const h8v*)(hb + (long)i0 * HID);
        h8v a1 = *(const h8v*)(hb + (long)i1 * HID);
        h8v a2 = *(const h8v*)(hb + (long)i2 * HID);
        h8v a3 = *(const h8v*)(hb + (long)i3 * HID);
        h8v a4 = *(const h8v*)(hb + (long)i4 * HID);
        h8v a5 = *(const h8v*)(hb + (long)i5 * HID);
        h8v a6 = *(const h8v*)(hb + (long)i6 * HID);
        h8v a7 = *(const h8v*)(hb + (long)i7 * HID);
#pragma unroll
        for (int j = 0; j < 8; j++)
            acc[j] += (((float)a0[j] + (float)a1[j]) + ((float)a2[j] + (float)a3[j])) +
                      (((float)a4[j] + (float)a5[j]) + ((float)a6[j] + (float)a7[j]));
    }
    for (; p < end; ++p) {
        int i0 = csr[p];
        h8v a0 = *(const h8v*)(hb + (long)i0 * HID);
#pragma unroll
        for (int j = 0; j < 8; j++) acc[j] += (float)a0[j];
    }

    float nd = active ? ndst[node] : 0.f;
    float ns = active ? nsrc[node] : 0.f;
    float x[8];
#pragma unroll
    for (int j = 0; j < 8; j++)
        x[j] = fmaxf(acc[j] * nd + b1[fl * 8 + j], 0.f) * ns;

    float q[NCLS];
#pragma unroll
    for (int c = 0; c < NCLS; c++) {
        float s = 0.f;
#pragma unroll
        for (int j = 0; j < 8; j++) s += x[j] * W2[(fl * 8 + j) * NCLS + c];
        q[c] = s;
    }
#pragma unroll
    for (int c = 0; c < NCLS; c++) {
#pragma unroll
        for (int off = 1; off < 16; off <<= 1) q[c] += __shfl_xor(q[c], off);
    }
    if (active) {
        if (fl < NCLS) h2p[(long)node * 8 + fl] = q[fl];
        if (fl == 7) h2p[(long)node * 8 + 7] = 0.f;
    }
}

// per dst node: out = (sum h2[src]) * nd + b2  (h2 stride-8, 2x float4 per edge)
__global__ __launch_bounds__(256) void agg2_kernel(const float* __restrict__ h2p,
                                                   const int* __restrict__ csr,
                                                   const int* __restrict__ rowptr,
                                                   const int* __restrict__ deg,
                                                   const float* __restrict__ ndst,
                                                   const float* __restrict__ b2,
                                                   float* __restrict__ out) {
    int wid = threadIdx.x >> 6, lane = threadIdx.x & 63;
    int node = blockIdx.x * 4 + wid;
    if (node >= N_NODES) return;
    int rp = rowptr[node], end = rp + deg[node];
    float a0 = 0.f, a1 = 0.f, a2 = 0.f, a3 = 0.f, a4 = 0.f, a5 = 0.f, a6 = 0.f;
    for (int p = rp + lane; p < end; p += 64) {
        int s = csr[p];
        const float4* r = (const float4*)(h2p + (long)s * 8);
        float4 lo = r[0], hi = r[1];
        a0 += lo.x; a1 += lo.y; a2 += lo.z; a3 += lo.w;
        a4 += hi.x; a5 += hi.y; a6 += hi.z;
    }
    float nd = ndst[node];
    float acc[NCLS] = {a0, a1, a2, a3, a4, a5, a6};
#pragma unroll
    for (int c = 0; c < NCLS; c++) {
        float v = acc[c];
#pragma unroll
        for (int off = 1; off < 64; off <<= 1) v += __shfl_xor(v, off);
        if (lane == c) out[(long)node * NCLS + c] = v * nd + b2[c];
    }
}

extern "C" void kernel_launch(void* const* d_in, const int* in_sizes, int n_in,
                              void* d_out, int out_size, void* d_ws, size_t ws_size,
                              hipStream_t stream) {
    const float* X  = (const float*)d_in[0];
    const int* src  = (const int*)d_in[1];
    const int* dst  = (const int*)d_in[2];
    const float* W1 = (const float*)d_in[3];
    const float* b1 = (const float*)d_in[4];
    const float* W2 = (const float*)d_in[5];
    const float* b2 = (const float*)d_in[6];
    float* out = (float*)d_out;

    char* ws = (char*)d_ws;
    int* deg_src = (int*)(ws + O_DEG_SRC);
    int* deg_dst = (int*)(ws + O_DEG_DST);
    int* cursor  = (int*)(ws + O_CURSOR);
    int* rowptr  = (int*)(ws + O_ROWPTR);
    float* nsrc  = (float*)(ws + O_NSRC);
    float* ndst  = (float*)(ws + O_NDST);
    int* bsum    = (int*)(ws + O_BSUM);
    int* boff    = (int*)(ws + O_BOFF);
    int* csr     = (int*)(ws + O_CSR);
    _Float16* h  = (_Float16*)(ws + O_H);
    float* h2p   = (float*)(ws + O_H2);
    _Float16* W1S = (_Float16*)(ws + O_W1S);

    const int nb = (N_NODES + 255) / 256;  // 196
    prep_kernel<<<237, 256, 0, stream>>>((int4*)ws, W1, W1S);
    deg_kernel<<<(N_EDGES / 4 + 255) / 256, 256, 0, stream>>>((const int4*)src, (const int4*)dst,
                                                              deg_src, deg_dst);
    scan1_kernel<<<nb, 256, 0, stream>>>(deg_dst, rowptr, bsum);
    scan2_kernel<<<1, 256, 0, stream>>>(bsum, boff, nb);
    scan3_kernel<<<nb, 256, 0, stream>>>(rowptr, deg_dst, deg_src, boff, nsrc, ndst);

    mega_kernel<<<GEMM_BLOCKS + FILL_BLOCKS, 256, 0, stream>>>(
        X, W1S, nsrc, h, (const int4*)src, (const int4*)dst, rowptr, cursor, csr);

    agg1_kernel<<<(N_NODES + 15) / 16, 256, 0, stream>>>(h, csr, rowptr, deg_dst, ndst, nsrc,
                                                         b1, W2, h2p);
    agg2_kernel<<<(N_NODES + 3) / 4, 256, 0, stream>>>(h2p, csr, rowptr, deg_dst, ndst, b2, out);
}